// Round 8
// baseline (1528.165 us; speedup 1.0000x reference)
//
#include <hip/hip_runtime.h>
#include <math.h>

typedef unsigned int   uint32;
typedef unsigned short ushort16;
typedef __attribute__((ext_vector_type(8))) short  short8;   // 8 bf16 (MFMA A/B frag)
typedef __attribute__((ext_vector_type(4))) float  floatx4;  // MFMA C/D frag

// Problem dims
#define Bb   512
#define QLn  128
#define ALn  512
#define En   300
#define Fn   400
#define OW   416      // packed output width: 400 real + 16 zero (832 B = 13*64)
#define EPAD 320      // e padded 300 -> 320 per shift; K_total = 3*320 = 960
#define NV   50001

static __device__ __forceinline__ float bf_lo(uint32 u) { return __uint_as_float(u << 16); }
static __device__ __forceinline__ float bf_hi(uint32 u) { return __uint_as_float(u & 0xffff0000u); }
static __device__ __forceinline__ ushort16 f2bf(float f) {
    uint32 u = __float_as_uint(f);
    uint32 r = (u + 0x7fffu + ((u >> 16) & 1u)) >> 16;   // RNE
    return (ushort16)r;
}
static __device__ __forceinline__ uint32 pack2(float a, float b) {
    return (uint32)f2bf(a) | ((uint32)f2bf(b) << 16);
}

// ---------------------------------------------------------------------------
// embcvt: embbf[v][0..320) = bf16(emb[v][0..300)), e>=300 zero.
// ---------------------------------------------------------------------------
__global__ __launch_bounds__(128) void embcvt_kernel(
        const float* __restrict__ emb, char* __restrict__ embbf)
{
    const int r = blockIdx.x, j = threadIdx.x;
    const float* er = emb + (size_t)r * En;
    uint32* orow = (uint32*)(embbf + (size_t)r * 640);
    for (int d = j; d < 160; d += 128) {
        uint32 v = 0;
        if (d < 150) {
            float2 f2v = *(const float2*)(er + 2 * d);
            v = pack2(f2v.x, f2v.y);
        }
        orow[d] = v;
    }
}

// ---------------------------------------------------------------------------
// prep_wt: Wt2[f][p] = W[f][e*3+kk] (p = kk*320+e), bf16, zero pad; bias2.
// ---------------------------------------------------------------------------
__global__ __launch_bounds__(256) void prep_wt(
        const float* __restrict__ W, const float* __restrict__ cb,
        ushort16* __restrict__ Wt2, float* __restrict__ bias2)
{
    const int f = blockIdx.x, t = threadIdx.x;
    for (int p2 = t; p2 < 480; p2 += 256) {
        int p = 2 * p2;
        float v0 = 0.f, v1 = 0.f;
        if (f < Fn) {
            int kk = p / EPAD, e = p - kk * EPAD;
            if (e < En)     v0 = W[(size_t)f * 900 + e * 3 + kk];
            if (e + 1 < En) v1 = W[(size_t)f * 900 + (e + 1) * 3 + kk];
        }
        *(uint32*)&Wt2[(size_t)f * 960 + p] = pack2(v0, v1);
    }
    if (t == 0) bias2[f] = (f < Fn) ? cb[f] : 0.f;
}

// ---------------------------------------------------------------------------
// prep_wp: Wp2[g][p] = sum_f U[f][g]*W[f][p900], fp32 accum, bf16 store.
// ---------------------------------------------------------------------------
__global__ __launch_bounds__(256) void prep_wp(
        const float* __restrict__ W, const float* __restrict__ U,
        ushort16* __restrict__ Wp2)
{
    __shared__ float Wl[400 * 32];
    const int t = threadIdx.x;
    const int pc = blockIdx.x, gc = blockIdx.y;
    const int kk = (pc * 32) / EPAD, e0 = pc * 32 - kk * EPAD;

    for (int i = t; i < 400 * 32; i += 256) {
        int f = i >> 5, j = i & 31, e = e0 + j;
        Wl[i] = (e < En) ? W[(size_t)f * 900 + e * 3 + kk] : 0.f;
    }
    __syncthreads();

    const int g = gc * 128 + (t >> 1);
    const int jh = (t & 1) * 16;
    float acc[16];
#pragma unroll
    for (int k = 0; k < 16; ++k) acc[k] = 0.f;

    for (int f = 0; f < Fn; ++f) {
        float uf = 0.f;
        if (g < Fn) uf = U[(size_t)f * Fn + g];
        const float* wl = Wl + f * 32 + jh;
#pragma unroll
        for (int k = 0; k < 16; ++k) acc[k] = fmaf(uf, wl[k], acc[k]);
    }
    ushort16* orow = Wp2 + (size_t)g * 960 + pc * 32 + jh;
#pragma unroll
    for (int k = 0; k < 16; k += 2)
        *(uint32*)&orow[k] = pack2(acc[k], acc[k + 1]);
}

__global__ __launch_bounds__(256) void prep_bp(
        const float* __restrict__ cb, const float* __restrict__ U,
        float* __restrict__ bp2)
{
    __shared__ float cbl[Fn];
    const int t = threadIdx.x;
    for (int f = t; f < Fn; f += 256) cbl[f] = cb[f];
    __syncthreads();
#pragma unroll
    for (int h = 0; h < 2; ++h) {
        int g = t + h * 256;
        float s = 0.f;
        if (g < Fn)
            for (int f = 0; f < Fn; ++f) s += cbl[f] * U[(size_t)f * Fn + g];
        bp2[g] = s;
    }
}

// ---------------------------------------------------------------------------
// conv_task_d: ONE WAVE computes 64 rows x NF*16 cols, K=960, ZERO LDS.
// MFMA A/B frag layout (row=lane&15, k=(lane>>4)*8+j) is a per-lane contiguous
// 16 B read of our K-major layouts -> direct global_load_dwordx4 with
// loop-invariant base pointers and immediate k-offsets. No barriers: the
// compiler software-pipelines loads across the fully unrolled K-loop.
// ---------------------------------------------------------------------------
template<int NF>
static __device__ __forceinline__ void conv_task_d(
        const int* __restrict__ tok, int l0, int L,   // l0 = wave row base
        const char* __restrict__ embbf,
        const char* __restrict__ W,      // [512][960] bf16, row stride 1920
        const float* __restrict__ biasv, int col0,    // wave col base (abs)
        ushort16* __restrict__ ob)       // block out ptr, pre-offset to row l0
{
    const int lane = threadIdx.x & 63;
    const int fm = lane & 15, q4 = lane >> 4;

    // A bases: token row for output row l0+m*16+fm, shift kk
    const char* pA[4][3];
#pragma unroll
    for (int m = 0; m < 4; ++m)
#pragma unroll
        for (int kk = 0; kk < 3; ++kk) {
            const int pos = l0 + m * 16 + fm - 1 + kk;
            const int tk = (pos >= 0 && pos < L) ? tok[pos] : 0;
            pA[m][kk] = embbf + (size_t)tk * 640 + q4 * 16;
        }
    const char* pB[NF];
#pragma unroll
    for (int n = 0; n < NF; ++n)
        pB[n] = W + (size_t)(col0 + n * 16 + fm) * 1920 + q4 * 16;

    floatx4 acc[4][NF];
    const floatx4 zz = {0.f, 0.f, 0.f, 0.f};
#pragma unroll
    for (int m = 0; m < 4; ++m)
#pragma unroll
        for (int n = 0; n < NF; ++n) acc[m][n] = zz;

#pragma unroll
    for (int kk = 0; kk < 3; ++kk) {
#pragma unroll
        for (int ks = 0; ks < 10; ++ks) {
            short8 af[4], bf[NF];
#pragma unroll
            for (int m = 0; m < 4; ++m)
                af[m] = *(const short8*)(pA[m][kk] + ks * 64);
#pragma unroll
            for (int n = 0; n < NF; ++n)
                bf[n] = *(const short8*)(pB[n] + kk * 640 + ks * 64);
#pragma unroll
            for (int m = 0; m < 4; ++m)
#pragma unroll
                for (int n = 0; n < NF; ++n)
                    acc[m][n] = __builtin_amdgcn_mfma_f32_16x16x32_bf16(
                        af[m], bf[n], acc[m][n], 0, 0, 0);
        }
    }

    // epilogue: +bias, bf16, store (C/D: col=lane&15, row=(lane>>4)*4+reg)
    float bn[NF];
#pragma unroll
    for (int n = 0; n < NF; ++n) bn[n] = biasv[col0 + n * 16 + fm];
#pragma unroll
    for (int m = 0; m < 4; ++m) {
        const int row = m * 16 + q4 * 4;
#pragma unroll
        for (int n = 0; n < NF; ++n) {
            const int col = col0 + n * 16 + fm;
#pragma unroll
            for (int r = 0; r < 4; ++r)
                ob[(size_t)(row + r) * OW + col] = f2bf(acc[m][n][r] + bn[n]);
        }
    }
}

// conv_direct: 24 tasks per batch, XCD-affine (all tasks of batch b on XCD b&7
// so gathered emb rows are L2-local; each row read by 4 col-blocks).
//  j24<12 : A main,  z=j24%3 (128 cols), rt=j24/3 (128-row tile)
//  12..17 : Q main,  z=(j24-12)%3, wsel=(j24-12)/3
//  18..21 : A rem (cols 384..416), rt=j24-18
//  22..23 : Q rem, wsel=j24-22
__global__ __launch_bounds__(256) void conv_direct(
        const int* __restrict__ question, const int* __restrict__ answer,
        const char* __restrict__ embbf,
        const char* __restrict__ Wt2, const char* __restrict__ Wp2,
        const float* __restrict__ bias2, const float* __restrict__ bp2,
        ushort16* __restrict__ qb, ushort16* __restrict__ qpb,
        ushort16* __restrict__ ab, int nb, int nbB)
{
    const int bx = blockIdx.x;
    const int xcd = bx & 7;
    const int r = bx >> 3;
    const int j24 = r / nbB;
    const int bh = r - j24 * nbB;
    const int b = bh * 8 + xcd;
    if (b >= nb) return;
    const int w = threadIdx.x >> 6;
    const int wr = w >> 1, wc = w & 1;

    if (j24 < 12) {
        const int z = j24 % 3, rt = j24 / 3;
        const int l0 = rt * 128 + wr * 64;
        conv_task_d<4>(answer + (size_t)b * ALn, l0, ALn, embbf, Wt2, bias2,
                       z * 128 + wc * 64, ab + ((size_t)b * ALn + l0) * OW);
    } else if (j24 < 18) {
        const int q6 = j24 - 12, z = q6 % 3, wsel = q6 / 3;
        const int l0 = wr * 64;
        conv_task_d<4>(question + (size_t)b * QLn, l0, QLn, embbf,
                       wsel ? Wp2 : Wt2, wsel ? bp2 : bias2,
                       z * 128 + wc * 64,
                       (wsel ? qpb : qb) + ((size_t)b * QLn + l0) * OW);
    } else if (j24 < 22) {
        const int rt = j24 - 18;
        const int l0 = rt * 128 + wr * 64;
        conv_task_d<1>(answer + (size_t)b * ALn, l0, ALn, embbf, Wt2, bias2,
                       384 + wc * 16, ab + ((size_t)b * ALn + l0) * OW);
    } else {
        const int wsel = j24 - 22;
        const int l0 = wr * 64;
        conv_task_d<1>(question + (size_t)b * QLn, l0, QLn, embbf,
                       wsel ? Wp2 : Wt2, wsel ? bp2 : bias2,
                       384 + wc * 16,
                       (wsel ? qpb : qb) + ((size_t)b * QLn + l0) * OW);
    }
}

// ---------------------------------------------------------------------------
// fused_g: block (b, a-chunk c). Gpre = Q' A^T (K=416), direct-frag loads,
// zero staging LDS. Emits per-chunk row maxes and col maxes.
// ---------------------------------------------------------------------------
__global__ __launch_bounds__(256) void fused_g(
        const ushort16* __restrict__ Qp,   // [nb][128][416]
        const ushort16* __restrict__ Av,   // [nb][512][416]
        float* __restrict__ rowPart,       // [nb][4][128]
        float* __restrict__ colMg,         // [nb][512]
        int nb)
{
    __shared__ float rowM2[128][2];
    __shared__ float colM2[128][2];

    const int t = threadIdx.x, lane = t & 63, w = t >> 6;
    const int bx = blockIdx.x;
    const int xcd = bx & 7, rest = bx >> 3;
    const int c = rest & 3, g = rest >> 2;
    const int T = g * 8 + xcd;
    if (T >= nb) return;
    const int b = T;
    const int wr = w >> 1, wc = w & 1;
    const int fm = lane & 15, q4 = lane >> 4;

    const char* Qpb = (const char*)Qp + (size_t)b * 106496;
    const char* Ab  = (const char*)Av + (size_t)b * 425984 + (size_t)c * 106496;

    const char* pQ[4];
    const char* pA[4];
#pragma unroll
    for (int m = 0; m < 4; ++m)
        pQ[m] = Qpb + (size_t)(wr * 64 + m * 16 + fm) * 832 + q4 * 16;
#pragma unroll
    for (int n = 0; n < 4; ++n)
        pA[n] = Ab + (size_t)(wc * 64 + n * 16 + fm) * 832 + q4 * 16;

    floatx4 acc[4][4];
    const floatx4 zz = {0.f, 0.f, 0.f, 0.f};
#pragma unroll
    for (int m = 0; m < 4; ++m)
#pragma unroll
        for (int n = 0; n < 4; ++n) acc[m][n] = zz;

#pragma unroll
    for (int ks = 0; ks < 13; ++ks) {
        short8 qa[4], aa_[4];
#pragma unroll
        for (int m = 0; m < 4; ++m) qa[m]  = *(const short8*)(pQ[m] + ks * 64);
#pragma unroll
        for (int n = 0; n < 4; ++n) aa_[n] = *(const short8*)(pA[n] + ks * 64);
#pragma unroll
        for (int m = 0; m < 4; ++m)
#pragma unroll
            for (int n = 0; n < 4; ++n)
                acc[m][n] = __builtin_amdgcn_mfma_f32_16x16x32_bf16(
                    qa[m], aa_[n], acc[m][n], 0, 0, 0);
    }

    // row maxes (q rows): max over n-frags, xor-reduce over fm (cols)
#pragma unroll
    for (int m = 0; m < 4; ++m)
#pragma unroll
        for (int r2 = 0; r2 < 4; ++r2) {
            float v = fmaxf(fmaxf(acc[m][0][r2], acc[m][1][r2]),
                            fmaxf(acc[m][2][r2], acc[m][3][r2]));
            v = fmaxf(v, __shfl_xor(v, 1));
            v = fmaxf(v, __shfl_xor(v, 2));
            v = fmaxf(v, __shfl_xor(v, 4));
            v = fmaxf(v, __shfl_xor(v, 8));
            if (fm == 0) rowM2[wr * 64 + m * 16 + q4 * 4 + r2][wc] = v;
        }
    // col maxes: max over (m, reg), xor-reduce over row quads
#pragma unroll
    for (int n = 0; n < 4; ++n) {
        float v = -1e30f;
#pragma unroll
        for (int m = 0; m < 4; ++m)
#pragma unroll
            for (int r2 = 0; r2 < 4; ++r2) v = fmaxf(v, acc[m][n][r2]);
        v = fmaxf(v, __shfl_xor(v, 16));
        v = fmaxf(v, __shfl_xor(v, 32));
        if (lane < 16) colM2[wc * 64 + n * 16 + lane][wr] = v;
    }
    __syncthreads();
    if (t < 128) {
        rowPart[((size_t)b * 4 + c) * 128 + t] = fmaxf(rowM2[t][0], rowM2[t][1]);
        colMg[(size_t)b * 512 + c * 128 + t]   = fmaxf(colM2[t][0], colM2[t][1]);
    }
}

// ---------------------------------------------------------------------------
// pooling: pool_parts (nb x 5 blocks) + pool_cos (nb)
// ---------------------------------------------------------------------------
static __device__ __forceinline__ float block_reduce_max(float v, volatile float* red) {
    int t = threadIdx.x;
    red[t] = v; __syncthreads();
    for (int s = 128; s > 0; s >>= 1) {
        if (t < s) red[t] = fmaxf(red[t], red[t + s]);
        __syncthreads();
    }
    float r = red[0]; __syncthreads();
    return r;
}
static __device__ __forceinline__ float block_reduce_sum(float v, volatile float* red) {
    int t = threadIdx.x;
    red[t] = v; __syncthreads();
    for (int s = 128; s > 0; s >>= 1) {
        if (t < s) red[t] = red[t] + red[t + s];
        __syncthreads();
    }
    float r = red[0]; __syncthreads();
    return r;
}

__global__ __launch_bounds__(256) void pool_parts(
        const ushort16* __restrict__ Qv,   // [nb][128][416]
        const ushort16* __restrict__ Av,   // [nb][512][416]
        const float* __restrict__ rowPart, // [nb][4][128]
        const float* __restrict__ colMg,   // [nb][512]
        float* __restrict__ rqv,           // [nb][416]
        float* __restrict__ rav)           // [nb][4][416]
{
    __shared__ float red[256];
    __shared__ float wgt[128];
    const int b = blockIdx.x, j = blockIdx.y, t = threadIdx.x;

    if (j == 0) {
        float v = -1e30f;
        if (t < QLn) {
            const float* rp = rowPart + (size_t)b * 512;
            float rm = fmaxf(fmaxf(rp[t], rp[128 + t]), fmaxf(rp[256 + t], rp[384 + t]));
            v = tanhf(rm);
        }
        float vmax = block_reduce_max(v, red);
        float ex = (t < QLn) ? __expf(v - vmax) : 0.f;
        float ssum = block_reduce_sum(ex, red);
        if (t < QLn) wgt[t] = ex / ssum;
        __syncthreads();
        float rq0 = 0.f, rq1 = 0.f;
        if (t < 208) {
            const uint32* Qb32 = (const uint32*)((const char*)Qv + (size_t)b * 106496);
#pragma unroll 4
            for (int q = 0; q < QLn; ++q) {
                float wv = wgt[q];
                uint32 u = Qb32[q * 208 + t];
                rq0 = fmaf(bf_lo(u), wv, rq0);
                rq1 = fmaf(bf_hi(u), wv, rq1);
            }
            rqv[(size_t)b * 416 + 2 * t]     = rq0;
            rqv[(size_t)b * 416 + 2 * t + 1] = rq1;
        }
    } else {
        float c0 = tanhf(colMg[(size_t)b * 512 + t]);
        float c1 = tanhf(colMg[(size_t)b * 512 + 256 + t]);
        float cmax = block_reduce_max(fmaxf(c0, c1), red);
        float e0 = __expf(c0 - cmax), e1 = __expf(c1 - cmax);
        float csum = block_reduce_sum(e0 + e1, red);
        const int a0 = (j - 1) * 128;
        if (t < 128)
            wgt[t] = __expf(tanhf(colMg[(size_t)b * 512 + a0 + t]) - cmax) / csum;
        __syncthreads();
        float ra0 = 0.f, ra1 = 0.f;
        if (t < 208) {
            const uint32* Ab32 = (const uint32*)((const char*)Av + (size_t)b * 425984);
#pragma unroll 4
            for (int a = 0; a < 128; ++a) {
                float wv = wgt[a];
                uint32 u = Ab32[(size_t)(a0 + a) * 208 + t];
                ra0 = fmaf(bf_lo(u), wv, ra0);
                ra1 = fmaf(bf_hi(u), wv, ra1);
            }
            rav[((size_t)b * 4 + (j - 1)) * 416 + 2 * t]     = ra0;
            rav[((size_t)b * 4 + (j - 1)) * 416 + 2 * t + 1] = ra1;
        }
    }
}

__global__ __launch_bounds__(256) void pool_cos(
        const float* __restrict__ rqv, const float* __restrict__ rav,
        float* __restrict__ out)
{
    __shared__ float red[256];
    const int b = blockIdx.x, t = threadIdx.x;
    float rq0 = 0.f, rq1 = 0.f, ra0 = 0.f, ra1 = 0.f;
    if (t < 208) {
        rq0 = rqv[(size_t)b * 416 + 2 * t];
        rq1 = rqv[(size_t)b * 416 + 2 * t + 1];
        const float* rb = rav + (size_t)b * 4 * 416;
#pragma unroll
        for (int p = 0; p < 4; ++p) {
            ra0 += rb[p * 416 + 2 * t];
            ra1 += rb[p * 416 + 2 * t + 1];
        }
    }
    float dd  = block_reduce_sum(rq0 * ra0 + rq1 * ra1, red);
    float qq  = block_reduce_sum(rq0 * rq0 + rq1 * rq1, red);
    float aam = block_reduce_sum(ra0 * ra0 + ra1 * ra1, red);
    if (t == 0) {
        float nq = fmaxf(sqrtf(qq), 1e-8f);
        float na = fmaxf(sqrtf(aam), 1e-8f);
        out[b] = dd / (nq * na);
    }
}

// ---------------------------------------------------------------------------
// launch — ws_size-adaptive balanced batch chunking (pure function of ws_size)
// ---------------------------------------------------------------------------
extern "C" void kernel_launch(void* const* d_in, const int* in_sizes, int n_in,
                              void* d_out, int out_size, void* d_ws, size_t ws_size,
                              hipStream_t stream)
{
    const int*   question = (const int*)d_in[0];
    const int*   answer   = (const int*)d_in[1];
    const float* emb      = (const float*)d_in[2];
    const float* conv_w   = (const float*)d_in[3];
    const float* conv_b   = (const float*)d_in[4];
    const float* U        = (const float*)d_in[5];
    float* out = (float*)d_out;
    char* ws = (char*)d_ws;

    const size_t WT2B   = (size_t)512 * 960 * 2;         // 983,040
    const size_t EMBB   = (size_t)NV * 640;              // 32,000,640
    const size_t FIXED0 = 2 * WT2B + 4096;               // 1,970,176
    const size_t FIXED  = FIXED0 + EMBB;                 // 33,970,816
    const size_t QB     = (size_t)QLn * OW * 2;          // 106,496
    const size_t AB     = (size_t)ALn * OW * 2;          // 425,984
    const size_t MXB    = 4096 + 1664 + 6656;            // rowP+colM+rqv+rav
    const size_t PER_B  = 2 * QB + AB + MXB;             // 651,392

    size_t avail = (ws_size > FIXED) ? (ws_size - FIXED) : 0;
    int CB = (int)(avail / PER_B);
    if (CB > Bb) CB = Bb;
    if (CB < 1)  CB = 1;
    int nch = (Bb + CB - 1) / CB;
    int CBe = (Bb + nch - 1) / nch;

    char*  wt2   = ws;
    char*  wp2   = ws + WT2B;
    float* bias2 = (float*)(ws + 2 * WT2B);
    float* bp2   = (float*)(ws + 2 * WT2B + 2048);
    char*  embbf = ws + FIXED0;
    char*  qb    = ws + FIXED;
    char*  qpb   = qb  + (size_t)CB * QB;
    char*  ab    = qpb + (size_t)CB * QB;
    float* rowP  = (float*)(ab + (size_t)CB * AB);
    float* colM  = rowP + (size_t)CB * 512;
    float* rqv   = colM + (size_t)CB * 512;
    float* rav   = rqv  + (size_t)CB * 416;

    embcvt_kernel<<<NV, 128, 0, stream>>>(emb, embbf);
    prep_wt<<<512, 256, 0, stream>>>(conv_w, conv_b, (ushort16*)wt2, bias2);
    prep_wp<<<dim3(30, 4), 256, 0, stream>>>(conv_w, U, (ushort16*)wp2);
    prep_bp<<<1, 256, 0, stream>>>(conv_b, U, bp2);

    for (int b0 = 0; b0 < Bb; b0 += CBe) {
        int nb = (Bb - b0 < CBe) ? (Bb - b0) : CBe;
        int nbB = (nb + 7) / 8;
        conv_direct<<<24 * nbB * 8, 256, 0, stream>>>(
            question + (size_t)b0 * QLn, answer + (size_t)b0 * ALn, embbf,
            wt2, wp2, bias2, bp2,
            (ushort16*)qb, (ushort16*)qpb, (ushort16*)ab, nb, nbB);

        int blocksG = ((nb + 7) / 8) * 8 * 4;
        fused_g<<<blocksG, 256, 0, stream>>>((const ushort16*)qpb, (const ushort16*)ab,
                                             rowP, colM, nb);
        pool_parts<<<dim3(nb, 5), 256, 0, stream>>>(
            (const ushort16*)qb, (const ushort16*)ab, rowP, colM, rqv, rav);
        pool_cos<<<nb, 256, 0, stream>>>(rqv, rav, out + b0);
    }
}